// Round 6
// baseline (45.699 us; speedup 1.0000x reference)
//
#include <hip/hip_runtime.h>
#include <math.h>

namespace {
constexpr int KB    = 16;        // spline bins
constexpr int OUTP  = 3*KB + 1;  // 49
constexpr int CDIM  = 64;
constexpr int HDIM  = 256;
constexpr int NCOL  = 1024;
constexpr int NROW  = 4096;
constexpr float BOUNDF = 5.0f;
constexpr float MBW_ = 0.001f;
constexpr float MBH_ = 0.001f;
constexpr float MD_  = 0.001f;
constexpr int PSTR = 51;  // 17 cumw | 17 cumh | 17 deriv
constexpr int NR   = 8;   // rows per block (MLP)
constexpr int NT   = 512; // threads per MLP block (8 waves)
}

// ---------------------------------------------------------------------------
// Kernel A: MLP -> spline params. 512 blocks x 8 waves (512 thr). 8-way
// split-K: wave w owns K-slice [K/8*w, ...); lane owns 4 consecutive cols ->
// coalesced float4 W loads, W read exactly once per block. Cross-wave
// reduction: two phases into ps[4] (waves 0-3 write, 4-7 float4-RMW), then
// 4-slot reduce. 45 KB LDS -> 2 blocks/CU = 16 waves/CU (grid-exact).
// ---------------------------------------------------------------------------
__global__ __launch_bounds__(NT, 4) void mlp_params_kernel(
    const float* __restrict__ cond,
    const float* __restrict__ W1, const float* __restrict__ b1,
    const float* __restrict__ W2, const float* __restrict__ b2,
    const float* __restrict__ W3, const float* __restrict__ b3,
    float* __restrict__ params)
{
    __shared__ float cond_s[NR][CDIM];       //  2   KB
    __shared__ float ps[4][NR][HDIM];        // 32   KB
    __shared__ float h_s[NR][HDIM];          //  8   KB (h1 then h2)
    __shared__ float p_s[NR][OUTP];          //  1.6 KB
    __shared__ float prm_s[NR][PSTR];        //  1.6 KB

    const int tid  = threadIdx.x;
    const int lane = tid & 63;
    const int wid  = tid >> 6;         // 0..7
    const int slot = wid & 3;
    const int row0 = blockIdx.x * NR;

    if (tid < NR*CDIM/4)
        *((float4*)&cond_s[0][0] + tid) = *((const float4*)(cond + (size_t)row0*CDIM) + tid);
    __syncthreads();

    // ---- layer 1: h1 = relu(cond @ W1 + b1); wave owns k in [8w, 8w+8)
    {
        float acc[NR][4];
        #pragma unroll
        for (int r = 0; r < NR; ++r)
            #pragma unroll
            for (int c = 0; c < 4; ++c) acc[r][c] = 0.f;

        #pragma unroll
        for (int kg = 0; kg < 2; ++kg) {
            const int k0 = 8*wid + 4*kg;
            float4 wv[4];
            #pragma unroll
            for (int kk = 0; kk < 4; ++kk)
                wv[kk] = *(const float4*)(W1 + (size_t)(k0+kk)*HDIM + 4*lane);
            #pragma unroll
            for (int r = 0; r < NR; ++r) {
                const float4 cv4 = *(const float4*)&cond_s[r][k0];
                const float cv[4] = {cv4.x, cv4.y, cv4.z, cv4.w};
                const float wf[4][4] = {{wv[0].x,wv[0].y,wv[0].z,wv[0].w},
                                        {wv[1].x,wv[1].y,wv[1].z,wv[1].w},
                                        {wv[2].x,wv[2].y,wv[2].z,wv[2].w},
                                        {wv[3].x,wv[3].y,wv[3].z,wv[3].w}};
                #pragma unroll
                for (int kk = 0; kk < 4; ++kk)
                    #pragma unroll
                    for (int c = 0; c < 4; ++c)
                        acc[r][c] = fmaf(cv[kk], wf[kk][c], acc[r][c]);
            }
        }
        if (wid < 4) {
            #pragma unroll
            for (int r = 0; r < NR; ++r)
                *(float4*)&ps[slot][r][4*lane] = make_float4(acc[r][0], acc[r][1], acc[r][2], acc[r][3]);
        }
        __syncthreads();
        if (wid >= 4) {
            #pragma unroll
            for (int r = 0; r < NR; ++r) {
                float4 p = *(const float4*)&ps[slot][r][4*lane];
                p.x += acc[r][0]; p.y += acc[r][1]; p.z += acc[r][2]; p.w += acc[r][3];
                *(float4*)&ps[slot][r][4*lane] = p;
            }
        }
        __syncthreads();
    }
    {   // reduce 4 slots -> h1 ; thread owns 4 consecutive cols of one row
        const int r  = tid >> 6;
        const int c0 = 4*(tid & 63);
        const float4 a = *(const float4*)&ps[0][r][c0];
        const float4 b = *(const float4*)&ps[1][r][c0];
        const float4 c = *(const float4*)&ps[2][r][c0];
        const float4 d = *(const float4*)&ps[3][r][c0];
        const float4 bb = *(const float4*)(b1 + c0);
        *(float4*)&h_s[r][c0] = make_float4(
            fmaxf(a.x+b.x+c.x+d.x+bb.x, 0.f), fmaxf(a.y+b.y+c.y+d.y+bb.y, 0.f),
            fmaxf(a.z+b.z+c.z+d.z+bb.z, 0.f), fmaxf(a.w+b.w+c.w+d.w+bb.w, 0.f));
    }
    __syncthreads();

    // ---- layer 2: h2 = relu(h1 @ W2 + b2); wave owns k in [32w, 32w+32)
    {
        float acc[NR][4];
        #pragma unroll
        for (int r = 0; r < NR; ++r)
            #pragma unroll
            for (int c = 0; c < 4; ++c) acc[r][c] = 0.f;

        float4 wn[4];
        #pragma unroll
        for (int kk = 0; kk < 4; ++kk)
            wn[kk] = *(const float4*)(W2 + (size_t)(32*wid+kk)*HDIM + 4*lane);

        #pragma unroll
        for (int kg = 0; kg < 8; ++kg) {
            const int k0 = 32*wid + 4*kg;
            float4 wv[4];
            #pragma unroll
            for (int kk = 0; kk < 4; ++kk) wv[kk] = wn[kk];
            if (kg < 7) {
                #pragma unroll
                for (int kk = 0; kk < 4; ++kk)
                    wn[kk] = *(const float4*)(W2 + (size_t)(k0+4+kk)*HDIM + 4*lane);
            }
            #pragma unroll
            for (int r = 0; r < NR; ++r) {
                const float4 hv4 = *(const float4*)&h_s[r][k0];
                const float hv[4] = {hv4.x, hv4.y, hv4.z, hv4.w};
                const float wf[4][4] = {{wv[0].x,wv[0].y,wv[0].z,wv[0].w},
                                        {wv[1].x,wv[1].y,wv[1].z,wv[1].w},
                                        {wv[2].x,wv[2].y,wv[2].z,wv[2].w},
                                        {wv[3].x,wv[3].y,wv[3].z,wv[3].w}};
                #pragma unroll
                for (int kk = 0; kk < 4; ++kk)
                    #pragma unroll
                    for (int c = 0; c < 4; ++c)
                        acc[r][c] = fmaf(hv[kk], wf[kk][c], acc[r][c]);
            }
        }
        if (wid < 4) {
            #pragma unroll
            for (int r = 0; r < NR; ++r)
                *(float4*)&ps[slot][r][4*lane] = make_float4(acc[r][0], acc[r][1], acc[r][2], acc[r][3]);
        }
        __syncthreads();
        if (wid >= 4) {
            #pragma unroll
            for (int r = 0; r < NR; ++r) {
                float4 p = *(const float4*)&ps[slot][r][4*lane];
                p.x += acc[r][0]; p.y += acc[r][1]; p.z += acc[r][2]; p.w += acc[r][3];
                *(float4*)&ps[slot][r][4*lane] = p;
            }
        }
        __syncthreads();
    }
    {   // reduce 4 slots -> h2 (overwrite h_s; all h1 reads completed)
        const int r  = tid >> 6;
        const int c0 = 4*(tid & 63);
        const float4 a = *(const float4*)&ps[0][r][c0];
        const float4 b = *(const float4*)&ps[1][r][c0];
        const float4 c = *(const float4*)&ps[2][r][c0];
        const float4 d = *(const float4*)&ps[3][r][c0];
        const float4 bb = *(const float4*)(b2 + c0);
        const float4 hn = make_float4(
            fmaxf(a.x+b.x+c.x+d.x+bb.x, 0.f), fmaxf(a.y+b.y+c.y+d.y+bb.y, 0.f),
            fmaxf(a.z+b.z+c.z+d.z+bb.z, 0.f), fmaxf(a.w+b.w+c.w+d.w+bb.w, 0.f));
        __syncthreads();                    // h1 reads done before overwrite
        *(float4*)&h_s[r][c0] = hn;
    }
    __syncthreads();

    // ---- layer 3: p = h2 @ W3 + b3; lane = output unit, wave owns k-slice
    {
        const int  o   = lane;
        const bool act = (o < OUTP);
        float acc[NR];
        #pragma unroll
        for (int r = 0; r < NR; ++r) acc[r] = 0.f;

        #pragma unroll 4
        for (int kg = 0; kg < 8; ++kg) {
            const int k0 = 32*wid + 4*kg;
            float wv[4];
            #pragma unroll
            for (int kk = 0; kk < 4; ++kk)
                wv[kk] = act ? W3[(size_t)(k0+kk)*OUTP + o] : 0.f;
            #pragma unroll
            for (int r = 0; r < NR; ++r) {
                const float4 hv = *(const float4*)&h_s[r][k0];
                acc[r] = fmaf(hv.x, wv[0], acc[r]);
                acc[r] = fmaf(hv.y, wv[1], acc[r]);
                acc[r] = fmaf(hv.z, wv[2], acc[r]);
                acc[r] = fmaf(hv.w, wv[3], acc[r]);
            }
        }
        if (act) {
            if (wid < 4) {
                #pragma unroll
                for (int r = 0; r < NR; ++r) ps[slot][r][o] = acc[r];
            }
        }
        __syncthreads();
        if (act && wid >= 4) {
            #pragma unroll
            for (int r = 0; r < NR; ++r) ps[slot][r][o] += acc[r];
        }
        __syncthreads();
    }
    for (int t = tid; t < NR*OUTP; t += NT) {
        const int r = t / OUTP;
        const int o = t - r*OUTP;
        p_s[r][o] = ps[0][r][o] + ps[1][r][o] + ps[2][r][o] + ps[3][r][o] + b3[o];
    }
    __syncthreads();

    // ---- softmax+cumsum (widths, heights) and softplus (derivs)
    if (tid < NR*3) {
        const int r   = tid / 3;
        const int seg = tid - 3*r;
        if (seg < 2) {
            const int   off   = (seg == 0) ? 0 : KB;
            const int   cbase = (seg == 0) ? 0 : 17;
            const float mb    = (seg == 0) ? MBW_ : MBH_;
            float m = -1e30f;
            #pragma unroll
            for (int i = 0; i < KB; ++i) m = fmaxf(m, p_s[r][off+i]);
            float e[KB];
            float s = 0.f;
            #pragma unroll
            for (int i = 0; i < KB; ++i) { e[i] = __expf(p_s[r][off+i] - m); s += e[i]; }
            const float span = (2.f*BOUNDF - (float)KB*mb) / s;
            float c = -BOUNDF;
            prm_s[r][cbase] = c;
            #pragma unroll
            for (int i = 0; i < KB; ++i) {
                c += mb + span*e[i];
                prm_s[r][cbase + 1 + i] = c;
            }
        } else {
            #pragma unroll
            for (int i = 0; i < KB+1; ++i) {
                const float x  = p_s[r][2*KB + i];
                const float sp = (x > 20.f) ? x : __logf(1.f + __expf(x));
                prm_s[r][34 + i] = MD_ + sp;
            }
        }
    }
    __syncthreads();

    for (int i = tid; i < NR*PSTR; i += NT)
        params[(size_t)row0*PSTR + i] = (&prm_s[0][0])[i];
}

// ---------------------------------------------------------------------------
// Kernel B: spline application. 4096 blocks (1 row each, ~1.3 KB LDS ->
// 8 blocks/CU resident). Packed 32B bin records: 1 ds_read_b128 + 1
// ds_read_b64 per element; single fast log for logdet.
// ---------------------------------------------------------------------------
__global__ __launch_bounds__(256) void spline_kernel(
    const float* __restrict__ y,
    const float* __restrict__ params,
    float* __restrict__ out,
    float* __restrict__ logdet)
{
    __shared__ float prm[PSTR];
    __shared__ float rec[KB][8];
    __shared__ float scan_s[KB];

    const int b   = blockIdx.x;
    const int tid = threadIdx.x;
    if (tid < PSTR) prm[tid] = params[(size_t)b*PSTR + tid];
    __syncthreads();
    if (tid < KB) {
        const int k = tid;
        rec[k][0] = prm[k];        rec[k][1] = prm[k+1];
        rec[k][2] = prm[17+k];     rec[k][3] = prm[17+k+1];
        rec[k][4] = prm[34+k];     rec[k][5] = prm[34+k+1];
        rec[k][6] = 0.f;           rec[k][7] = 0.f;
        scan_s[k] = prm[k+1];      // thresholds cumw[1..16]
    }
    __syncthreads();

    float cw[KB];
    #pragma unroll
    for (int q = 0; q < 4; ++q) {
        const float4 t4 = *(const float4*)&scan_s[4*q];   // uniform broadcast
        cw[4*q+0] = t4.x; cw[4*q+1] = t4.y; cw[4*q+2] = t4.z; cw[4*q+3] = t4.w;
    }

    const size_t base = (size_t)b * NCOL + 4*tid;
    const float4 yv   = *(const float4*)(y + base);
    const float  yy[4] = {yv.x, yv.y, yv.z, yv.w};
    float ov[4], lv[4];

    #pragma unroll
    for (int i = 0; i < 4; ++i) {
        const float yi = yy[i];
        const bool outside = (yi < -BOUNDF) || (yi > BOUNDF);
        const float xc = fminf(fmaxf(yi, -BOUNDF), BOUNDF);
        int bin = 0;
        #pragma unroll
        for (int k = 0; k < KB; ++k) bin += (xc >= cw[k]) ? 1 : 0;
        bin = min(bin, KB-1);

        const float4 lo = *(const float4*)&rec[bin][0];   // ds_read_b128
        const float2 hi = *(const float2*)&rec[bin][4];   // ds_read_b64
        const float w  = lo.y - lo.x;
        const float hh = lo.w - lo.z;
        const float d0 = hi.x, d1 = hi.y;

        const float inv_w = __fdividef(1.f, w);
        const float delta = hh * inv_w;
        const float theta = (xc - lo.x) * inv_w;
        const float omt   = 1.f - theta;
        const float tt    = theta * theta;
        const float tomt  = theta * omt;
        const float num   = hh * (delta*tt + d0*tomt);
        const float den   = delta + (d0 + d1 - 2.f*delta)*tomt;
        const float o     = lo.z + __fdividef(num, den);
        const float der_num = fmaxf(delta*delta*(d1*tt + 2.f*delta*tomt + d0*omt*omt), 1e-12f);
        const float der_den = fmaxf(den*den, 1e-12f);
        const float ld      = __logf(__fdividef(der_num, der_den));

        ov[i] = outside ? yi : o;
        lv[i] = outside ? 0.f : ld;
    }

    *(float4*)(out + base)    = make_float4(ov[0], ov[1], ov[2], ov[3]);
    *(float4*)(logdet + base) = make_float4(lv[0], lv[1], lv[2], lv[3]);
}

extern "C" void kernel_launch(void* const* d_in, const int* in_sizes, int n_in,
                              void* d_out, int out_size, void* d_ws, size_t ws_size,
                              hipStream_t stream) {
    const float* cond = (const float*)d_in[0];
    const float* y    = (const float*)d_in[1];
    const float* W1   = (const float*)d_in[2];
    const float* b1   = (const float*)d_in[3];
    const float* W2   = (const float*)d_in[4];
    const float* b2   = (const float*)d_in[5];
    const float* W3   = (const float*)d_in[6];
    const float* b3   = (const float*)d_in[7];

    float* out    = (float*)d_out;
    float* logdet = out + (size_t)NROW * NCOL;
    float* params = (float*)d_ws;   // 4096 * 51 floats = 0.84 MB

    mlp_params_kernel<<<NROW/NR, NT, 0, stream>>>(cond, W1, b1, W2, b2, W3, b3, params);
    spline_kernel<<<NROW, 256, 0, stream>>>(y, params, out, logdet);
}